// Round 7
// baseline (146.782 us; speedup 1.0000x reference)
//
#include <hip/hip_runtime.h>
#include <math.h>

#define N 3072
#define H 64
#define CAUS 16
#define CSD 32
#define GAT_ALPHA 0.35f
#define SLICES 16
#define JSL (N / SLICES)  // 192
#define NH (N * H)        // 196608
#define HALF 1536
typedef unsigned long long u64;
typedef unsigned short u16;
typedef __attribute__((ext_vector_type(4))) float f32x4;
typedef __attribute__((ext_vector_type(8))) short s16x8;
struct alignas(8) u16x4 { u16 x, y, z, w; };
struct T4 { float4 r[4]; };

// f32 -> bf16 round-to-nearest-even
__device__ inline u16 f2bf(float f) {
  unsigned u = __builtin_bit_cast(unsigned, f);
  u += 0x7fffu + ((u >> 16) & 1u);
  return (u16)(u >> 16);
}

// Transpose-staging: src f32 [k][m] (stride ld); thread t loads 4k x 4m micro-tile.
__device__ inline T4 t_load(const float* __restrict__ src, int ld, int t) {
  int k4 = (t >> 4) * 4, m4 = (t & 15) * 4;
  T4 o;
#pragma unroll
  for (int d = 0; d < 4; d++)
    o.r[d] = *(const float4*)(src + (size_t)(k4 + d) * ld + m4);
  return o;
}
__device__ inline void t_store(u16 (&dst)[64][72], const T4& v, int t) {
  int k4 = (t >> 4) * 4, m4 = (t & 15) * 4;
  u16x4 c0 = {f2bf(v.r[0].x), f2bf(v.r[1].x), f2bf(v.r[2].x), f2bf(v.r[3].x)};
  u16x4 c1 = {f2bf(v.r[0].y), f2bf(v.r[1].y), f2bf(v.r[2].y), f2bf(v.r[3].y)};
  u16x4 c2 = {f2bf(v.r[0].z), f2bf(v.r[1].z), f2bf(v.r[2].z), f2bf(v.r[3].z)};
  u16x4 c3 = {f2bf(v.r[0].w), f2bf(v.r[1].w), f2bf(v.r[2].w), f2bf(v.r[3].w)};
  *(u16x4*)&dst[m4 + 0][k4] = c0;
  *(u16x4*)&dst[m4 + 1][k4] = c1;
  *(u16x4*)&dst[m4 + 2][k4] = c2;
  *(u16x4*)&dst[m4 + 3][k4] = c3;
}

// 64x64 MFMA core (for k_mmpack / k_mmdec): D += A_s · B_s^T over K=64.
__device__ inline void mfma_tile(const u16 (&As)[64][72], const u16 (&Bs)[64][72],
                                 f32x4 acc[2][2], int wi, int wf, int il, int kg) {
#pragma unroll
  for (int kk = 0; kk < 64; kk += 32) {
    s16x8 a0 = *(const s16x8*)&As[wi * 32 + il][kk + kg * 8];
    s16x8 a1 = *(const s16x8*)&As[wi * 32 + 16 + il][kk + kg * 8];
    s16x8 b0 = *(const s16x8*)&Bs[wf * 32 + il][kk + kg * 8];
    s16x8 b1 = *(const s16x8*)&Bs[wf * 32 + 16 + il][kk + kg * 8];
    acc[0][0] = __builtin_amdgcn_mfma_f32_16x16x32_bf16(a0, b0, acc[0][0], 0, 0, 0);
    acc[0][1] = __builtin_amdgcn_mfma_f32_16x16x32_bf16(a0, b1, acc[0][1], 0, 0, 0);
    acc[1][0] = __builtin_amdgcn_mfma_f32_16x16x32_bf16(a1, b0, acc[1][0], 0, 0, 0);
    acc[1][1] = __builtin_amdgcn_mfma_f32_16x16x32_bf16(a1, b1, acc[1][1], 0, 0, 0);
  }
}

__device__ inline void store_tile(float* __restrict__ op, int g0, int wi, int wf,
                                  int il, int kg, f32x4 acc[2][2]) {
#pragma unroll
  for (int ti = 0; ti < 2; ti++)
#pragma unroll
    for (int tf = 0; tf < 2; tf++) {
      int col = wf * 32 + tf * 16 + il;
      int rbase = g0 + wi * 32 + ti * 16 + kg * 4;
#pragma unroll
      for (int r = 0; r < 4; r++)
        op[(size_t)(rbase + r) * H + col] = acc[ti][tf][r];
    }
}

// ---------------------------------------------------------------------------
// Fused: blocks 0-767 = MFMA GEMM part[g][f] = x^T·Wgat (split-K 16);
//        blocks 768-1535 = adjacency bit-pack + degree rsqrt.
__global__ __launch_bounds__(256) void k_mmpack(const float* __restrict__ x,
                                                const float* __restrict__ Wgat,
                                                float* __restrict__ part,
                                                const int* __restrict__ adj,
                                                u64* __restrict__ packed,
                                                float* __restrict__ dis) {
  __shared__ u16 As[64][72];
  __shared__ u16 Bs[64][72];
  int bid = blockIdx.x;
  int t = threadIdx.x;
  if (bid >= 768) {  // ---- pack branch
    int row = (bid - 768) * 4 + (t >> 6);
    int lane = t & 63;
    const int* ar = adj + (size_t)row * N;
    int deg = 0;
    for (int w = 0; w < 48; w++) {
      int v = ar[w * 64 + lane];
      u64 m = __ballot(v > 0);
      if (lane == 0) packed[(size_t)row * 48 + w] = m;
      deg += (v > 0) ? 1 : 0;
    }
    for (int off = 32; off; off >>= 1) deg += __shfl_xor(deg, off);
    if (lane == 0) dis[row] = rsqrtf((float)deg + 1.0f);
    return;
  }
  // ---- mm branch
  int g0 = (bid % 48) * 64;
  int c0 = (bid / 48) * JSL;
  int w = t >> 6, lane = t & 63, il = lane & 15, kg = lane >> 4;
  int wi = w >> 1, wf = w & 1;
  f32x4 z = {0.f, 0.f, 0.f, 0.f};
  f32x4 acc[2][2] = {{z, z}, {z, z}};
  T4 av = t_load(x + (size_t)c0 * N + g0, N, t);
  T4 bv = t_load(Wgat + (size_t)c0 * H, H, t);
  for (int cb = 0; cb < JSL; cb += 64) {
    __syncthreads();
    t_store(As, av, t);
    t_store(Bs, bv, t);
    if (cb + 64 < JSL) {
      av = t_load(x + (size_t)(c0 + cb + 64) * N + g0, N, t);
      bv = t_load(Wgat + (size_t)(c0 + cb + 64) * H, H, t);
    }
    __syncthreads();
    mfma_tile(As, Bs, acc, wi, wf, il, kg);
  }
  store_tile(part + (size_t)(bid / 48) * NH, g0, wi, wf, il, kg, acc);
}

// ---------------------------------------------------------------------------
// Reduce 16 partial h buffers -> h f32, fused with s_dst/s_src dots.
__global__ __launch_bounds__(256) void k_reduce_sd(const float* __restrict__ src,
                                                   const float* __restrict__ a,
                                                   float* __restrict__ h,
                                                   float* __restrict__ sdst,
                                                   float* __restrict__ ssrc) {
  int row = blockIdx.x * 4 + (threadIdx.x >> 6);
  int lane = threadIdx.x & 63;
  size_t off = (size_t)row * H + lane;
  float v = 0.f;
#pragma unroll
  for (int p = 0; p < SLICES; p++) v += src[(size_t)p * NH + off];
  h[off] = v;
  float d1 = v * a[lane];
  float d2 = v * a[H + lane];
  for (int o = 32; o; o >>= 1) {
    d1 += __shfl_xor(d1, o);
    d2 += __shfl_xor(d2, o);
  }
  if (lane == 0) { sdst[row] = d1; ssrc[row] = d2; }
}

// ---------------------------------------------------------------------------
// Generic 16-way float4 partial reduce: dst = sum_p src[p].
__global__ __launch_bounds__(256) void k_reduce(const float4* __restrict__ src,
                                                float4* __restrict__ dst) {
  int idx = blockIdx.x * 256 + threadIdx.x;
  float4 v = {0, 0, 0, 0};
#pragma unroll
  for (int p = 0; p < SLICES; p++) {
    float4 u = src[(size_t)p * (NH / 4) + idx];
    v.x += u.x; v.y += u.y; v.z += u.z; v.w += u.w;
  }
  dst[idx] = v;
}

// ---------------------------------------------------------------------------
// Full-K masked aggregation, 16 output rows/block, 512 thr = 2 j-half groups.
// MODE 0: GCN -> h2 = relu(dis·acc), + ie[:, :64].
// MODE 1: GAT -> in-block Z + elu + full VAE (mu/lv/cs/ie-hi).
// MODE 2: GCN -> h1 = relu(dis·acc) kept in LDS, t2 = h1 @ W2 via MFMA.
template <int MODE>
__global__ __launch_bounds__(512) void k_agg(
    const float* __restrict__ hin, const u64* __restrict__ packed,
    const float* __restrict__ sdst, const float* __restrict__ ssrc,
    const float* __restrict__ dis, const float* __restrict__ eps,
    const float* __restrict__ Wmu, const float* __restrict__ bmu,
    const float* __restrict__ Wlv, const float* __restrict__ blv,
    const float* __restrict__ Wd, const float* __restrict__ bd,
    const float* __restrict__ W2,
    float* __restrict__ o0, float* __restrict__ ie,
    float* __restrict__ muo, float* __restrict__ lvo) {
  __shared__ u16 Hs[2][64][72];
  __shared__ u16 Ws[2][16][72];
  __shared__ float osum[4][256];
  __shared__ float hfin[16][68];
  __shared__ float zls[2][16];
  __shared__ float ssl[16];
  __shared__ float wmu_s[1024];
  __shared__ float wlv_s[1024];
  __shared__ float wd_s[2560];
  __shared__ float zvae[16][17];

  int t = threadIdx.x;
  int i0 = blockIdx.x * 16;
  int g = t >> 8, tt = t & 255;
  int w8 = t >> 6, wg = w8 & 3, l = t & 63;
  int il = l & 15, kg = l >> 4;
  int r = tt >> 4, jq = (tt & 15) * 4;

  if (MODE == 1) {
    for (int k = t; k < 1024; k += 512) { wmu_s[k] = Wmu[k]; wlv_s[k] = Wlv[k]; }
    for (int k = t; k < 2560; k += 512) wd_s[k] = Wd[k];
    if (t < 16) ssl[t] = ssrc[i0 + t];
  }
  __syncthreads();
  float sv = (MODE == 1) ? ssl[r] : 0.f;
  float zacc = 0.f;
  int jg = g * HALF;

  auto gen_w = [&](int j0, float (&wv)[4]) {
    u64 wb = packed[(size_t)(i0 + r) * 48 + (j0 >> 6)];
    if (MODE == 1) {
      float4 s4 = *(const float4*)(sdst + j0 + jq);
      float sf[4] = {s4.x, s4.y, s4.z, s4.w};
#pragma unroll
      for (int q = 0; q < 4; q++) {
        float e = sv + sf[q];
        e = e > 0.f ? e : GAT_ALPHA * e;
        float ww = ((wb >> (jq + q)) & 1ULL) ? __expf(e) : 0.f;
        wv[q] = ww;
        zacc += ww;
      }
    } else {
      float4 d4 = *(const float4*)(dis + j0 + jq);
      float df[4] = {d4.x, d4.y, d4.z, d4.w};
#pragma unroll
      for (int q = 0; q < 4; q++) {
        float cnt = (float)((wb >> (jq + q)) & 1ULL) +
                    ((i0 + r) == (j0 + jq + q) ? 1.f : 0.f);
        wv[q] = cnt * df[q];
      }
    }
  };

  f32x4 acc = {0.f, 0.f, 0.f, 0.f};
  T4 hv = t_load(hin + (size_t)jg * H, H, tt);
  float wv[4];
  gen_w(jg, wv);
  for (int js = 0; js < HALF; js += 64) {
    __syncthreads();
    t_store(Hs[g], hv, tt);
    u16x4 wb4 = {f2bf(wv[0]), f2bf(wv[1]), f2bf(wv[2]), f2bf(wv[3])};
    *(u16x4*)&Ws[g][r][jq] = wb4;
    if (js + 64 < HALF) {
      hv = t_load(hin + (size_t)(jg + js + 64) * H, H, tt);
      gen_w(jg + js + 64, wv);
    }
    __syncthreads();
#pragma unroll
    for (int kk = 0; kk < 64; kk += 32) {
      s16x8 a = *(const s16x8*)&Ws[g][il][kk + kg * 8];
      s16x8 b = *(const s16x8*)&Hs[g][wg * 16 + il][kk + kg * 8];
      acc = __builtin_amdgcn_mfma_f32_16x16x32_bf16(a, b, acc, 0, 0, 0);
    }
  }
  if (MODE == 1) {  // per-row Z partial (16-lane groups are row-pure)
    zacc += __shfl_xor(zacc, 1);
    zacc += __shfl_xor(zacc, 2);
    zacc += __shfl_xor(zacc, 4);
    zacc += __shfl_xor(zacc, 8);
    if ((l & 15) == 0) zls[g][r] = zacc;
  }
  if (g == 1) {
#pragma unroll
    for (int q = 0; q < 4; q++) osum[wg][l * 4 + q] = acc[q];
  }
  __syncthreads();
  if (g == 0) {
#pragma unroll
    for (int q = 0; q < 4; q++)
      hfin[kg * 4 + q][wg * 16 + il] = acc[q] + osum[wg][l * 4 + q];
  }
  __syncthreads();

  if (MODE == 0) {
    if (t < 256) {
      float dr = dis[i0 + r];
      float4 v;
      v.x = fmaxf(hfin[r][jq + 0] * dr, 0.f);
      v.y = fmaxf(hfin[r][jq + 1] * dr, 0.f);
      v.z = fmaxf(hfin[r][jq + 2] * dr, 0.f);
      v.w = fmaxf(hfin[r][jq + 3] * dr, 0.f);
      *(float4*)(o0 + (size_t)(i0 + r) * H + jq) = v;
      *(float4*)(ie + (size_t)(i0 + r) * 96 + jq) = v;
    }
  } else if (MODE == 2) {
    if (t < 256) {
      T4 w2v = t_load(W2, 64, tt);  // W2 [k][n] -> Hs[0][n][k]
      float dr = dis[i0 + r];
      u16x4 hb = {f2bf(fmaxf(hfin[r][jq + 0] * dr, 0.f)),
                  f2bf(fmaxf(hfin[r][jq + 1] * dr, 0.f)),
                  f2bf(fmaxf(hfin[r][jq + 2] * dr, 0.f)),
                  f2bf(fmaxf(hfin[r][jq + 3] * dr, 0.f))};
      *(u16x4*)&Ws[0][r][jq] = hb;
      t_store(Hs[0], w2v, tt);
    }
    __syncthreads();
    if (t < 256) {
      f32x4 a2 = {0.f, 0.f, 0.f, 0.f};
#pragma unroll
      for (int kk = 0; kk < 64; kk += 32) {
        s16x8 a = *(const s16x8*)&Ws[0][il][kk + kg * 8];
        s16x8 b = *(const s16x8*)&Hs[0][wg * 16 + il][kk + kg * 8];
        a2 = __builtin_amdgcn_mfma_f32_16x16x32_bf16(a, b, a2, 0, 0, 0);
      }
#pragma unroll
      for (int q = 0; q < 4; q++)
        o0[(size_t)(i0 + kg * 4 + q) * H + wg * 16 + il] = a2[q];
    }
  } else {  // MODE 1: Z-normalize + elu + VAE + diffusion fusion
    if (t < 256) {
      float zi = 1.0f / fmaxf(zls[0][r] + zls[1][r], 1e-30f);
#pragma unroll
      for (int q = 0; q < 4; q++) {
        float e = hfin[r][jq + q] * zi;
        hfin[r][jq + q] = e > 0.f ? e : __expf(e) - 1.f;
      }
    }
    __syncthreads();
    if (t < 256) {
      int kk = tt & 15;
      float mu = bmu[kk], lvv = blv[kk];
#pragma unroll 8
      for (int ll = 0; ll < 64; ll++) {
        float hvv = hfin[r][ll];
        mu += hvv * wmu_s[ll * 16 + kk];
        lvv += hvv * wlv_s[ll * 16 + kk];
      }
      float zc = mu + eps[(size_t)(i0 + r) * CAUS + kk] * __expf(0.5f * lvv);
      muo[(size_t)(i0 + r) * CAUS + kk] = mu;
      lvo[(size_t)(i0 + r) * CAUS + kk] = lvv;
      zvae[r][kk] = zc;
    }
    __syncthreads();
    {
      int rr = t >> 5, c = t & 31;
      float a = bd[c];
#pragma unroll 4
      for (int q = 0; q < 16; q++) a += zvae[rr][q] * wd_s[q * 32 + c];
#pragma unroll 8
      for (int ll = 0; ll < 64; ll++) a += hfin[rr][ll] * wd_s[(16 + ll) * 32 + c];
      float v = fmaxf(a, 0.f);
      o0[(size_t)(i0 + rr) * CSD + c] = v;
      ie[(size_t)(i0 + rr) * 96 + 64 + c] = v;
    }
  }
}

// ---------------------------------------------------------------------------
// Fused decoder + GEMM: xr tile = sigmoid(cs·Wdec+b) via decode-MFMA,
// writes xr (f32 out) and t1 partials = xr^T · Wg1 via main MFMA.
__global__ __launch_bounds__(256) void k_mmdec(const float* __restrict__ cs,
                                               const float* __restrict__ Wdec,
                                               const float* __restrict__ bdec,
                                               const float* __restrict__ Wg1,
                                               float* __restrict__ xr,
                                               float* __restrict__ outp) {
  __shared__ u16 As[64][72];
  __shared__ u16 Bs[64][72];
  __shared__ u16 Wd[64][48];
  __shared__ u16 Cs[64][48];
  __shared__ float bs_s[64];
  int t = threadIdx.x;
  int g0 = blockIdx.x * 64;
  int c0 = blockIdx.y * JSL;
  int w = t >> 6, lane = t & 63, il = lane & 15, kg = lane >> 4;
  int wi = w >> 1, wf = w & 1;
  {
    int q = t >> 4, m4 = (t & 15) * 4;
#pragma unroll
    for (int it = 0; it < 2; it++) {
      int qq = q + it * 16;
      float4 v = *(const float4*)(Wdec + (size_t)qq * N + g0 + m4);
      Wd[m4 + 0][qq] = f2bf(v.x);
      Wd[m4 + 1][qq] = f2bf(v.y);
      Wd[m4 + 2][qq] = f2bf(v.z);
      Wd[m4 + 3][qq] = f2bf(v.w);
    }
    if (t < 64) bs_s[t] = bdec[g0 + t];
  }
  int kr = t >> 3, q4 = (t & 7) * 4;
  float4 cv0 = *(const float4*)(cs + (size_t)(c0 + kr) * CSD + q4);
  float4 cv1 = *(const float4*)(cs + (size_t)(c0 + 32 + kr) * CSD + q4);
  T4 bv = t_load(Wg1 + (size_t)c0 * H, H, t);
  f32x4 z = {0.f, 0.f, 0.f, 0.f};
  f32x4 acc[2][2] = {{z, z}, {z, z}};
  for (int cb = 0; cb < JSL; cb += 64) {
    __syncthreads();
    Cs[kr][q4 + 0] = f2bf(cv0.x); Cs[kr][q4 + 1] = f2bf(cv0.y);
    Cs[kr][q4 + 2] = f2bf(cv0.z); Cs[kr][q4 + 3] = f2bf(cv0.w);
    Cs[kr + 32][q4 + 0] = f2bf(cv1.x); Cs[kr + 32][q4 + 1] = f2bf(cv1.y);
    Cs[kr + 32][q4 + 2] = f2bf(cv1.z); Cs[kr + 32][q4 + 3] = f2bf(cv1.w);
    t_store(Bs, bv, t);
    if (cb + 64 < JSL) {
      cv0 = *(const float4*)(cs + (size_t)(c0 + cb + 64 + kr) * CSD + q4);
      cv1 = *(const float4*)(cs + (size_t)(c0 + cb + 96 + kr) * CSD + q4);
      bv = t_load(Wg1 + (size_t)(c0 + cb + 64) * H, H, t);
    }
    __syncthreads();
    f32x4 dec[2][2] = {{z, z}, {z, z}};
    {
      s16x8 a0 = *(const s16x8*)&Wd[wi * 32 + il][kg * 8];
      s16x8 a1 = *(const s16x8*)&Wd[wi * 32 + 16 + il][kg * 8];
      s16x8 b0 = *(const s16x8*)&Cs[wf * 32 + il][kg * 8];
      s16x8 b1 = *(const s16x8*)&Cs[wf * 32 + 16 + il][kg * 8];
      dec[0][0] = __builtin_amdgcn_mfma_f32_16x16x32_bf16(a0, b0, dec[0][0], 0, 0, 0);
      dec[0][1] = __builtin_amdgcn_mfma_f32_16x16x32_bf16(a0, b1, dec[0][1], 0, 0, 0);
      dec[1][0] = __builtin_amdgcn_mfma_f32_16x16x32_bf16(a1, b0, dec[1][0], 0, 0, 0);
      dec[1][1] = __builtin_amdgcn_mfma_f32_16x16x32_bf16(a1, b1, dec[1][1], 0, 0, 0);
    }
#pragma unroll
    for (int ti = 0; ti < 2; ti++)
#pragma unroll
      for (int tf = 0; tf < 2; tf++) {
        int kcol = wf * 32 + tf * 16 + il;
        int mbase = wi * 32 + ti * 16 + kg * 4;
        float4 sv4;
        float* svp = (float*)&sv4;
#pragma unroll
        for (int rr = 0; rr < 4; rr++) {
          float pre = dec[ti][tf][rr] + bs_s[mbase + rr];
          float sg = 1.f / (1.f + __expf(-pre));
          svp[rr] = sg;
          As[mbase + rr][kcol] = f2bf(sg);
        }
        *(float4*)(xr + (size_t)(c0 + cb + kcol) * N + g0 + mbase) = sv4;
      }
    __syncthreads();
    mfma_tile(As, Bs, acc, wi, wf, il, kg);
  }
  store_tile(outp + (size_t)blockIdx.y * NH, g0, wi, wf, il, kg, acc);
}

// ---------------------------------------------------------------------------
extern "C" void kernel_launch(void* const* d_in, const int* in_sizes, int n_in,
                              void* d_out, int out_size, void* d_ws, size_t ws_size,
                              hipStream_t stream) {
  const float* x    = (const float*)d_in[0];
  const int*   adj  = (const int*)d_in[1];
  const float* eps  = (const float*)d_in[2];
  const float* Wgat = (const float*)d_in[3];
  const float* agat = (const float*)d_in[4];
  const float* Wmu  = (const float*)d_in[5];
  const float* bmu  = (const float*)d_in[6];
  const float* Wlv  = (const float*)d_in[7];
  const float* blv  = (const float*)d_in[8];
  const float* Wdif = (const float*)d_in[9];
  const float* bdif = (const float*)d_in[10];
  const float* Wdec = (const float*)d_in[11];
  const float* bdec = (const float*)d_in[12];
  const float* Wg1  = (const float*)d_in[13];
  const float* Wg2  = (const float*)d_in[14];

  float* out = (float*)d_out;
  float* xr  = out;                       // (3072,3072)
  float* h2  = out + 9437184;             // (3072,64)
  float* ie  = out + 9633792;             // (3072,96)
  float* cs  = out + 9928704;             // (3072,32)
  float* muo = out + 10027008;            // (3072,16)
  float* lvo = out + 10076160;            // (3072,16)

  // Workspace (~16 MB of 256 MB)
  u64* packed = (u64*)d_ws;               // 3072*48 u64 = 1.18 MB
  float* wf   = (float*)d_ws + 294912;
  float* part = wf;                       // SLICES*NH f32 partials (reused 2x)
  float* h    = part + (size_t)SLICES * NH;
  float* t1   = h + NH;
  float* t2   = t1 + NH;
  float* sdst = t2 + NH;
  float* ssrc = sdst + N;
  float* dis  = ssrc + N;

  // 1: fused x^T@Wgat split-K + adjacency pack
  k_mmpack<<<1536, 256, 0, stream>>>(x, Wgat, part, adj, packed, dis);
  // 2: reduce partials -> h + attention dot products
  k_reduce_sd<<<768, 256, 0, stream>>>(part, agat, h, sdst, ssrc);
  // 3: GAT aggregation full-K + Z + elu + VAE + cs/ie-hi/mu/lv
  k_agg<1><<<192, 512, 0, stream>>>(h, packed, sdst, ssrc, dis, eps,
                                    Wmu, bmu, Wlv, blv, Wdif, bdif, nullptr,
                                    cs, ie, muo, lvo);
  // 4: fused decoder + GCN GEMM (xr output + t1 partials)
  k_mmdec<<<dim3(48, SLICES), 256, 0, stream>>>(cs, Wdec, bdec, Wg1, xr, part);
  // 5: reduce partials -> t1
  k_reduce<<<192, 256, 0, stream>>>((const float4*)part, (float4*)t1);
  // 6: GCN agg full-K on t1 + relu*dis + fused @W2 -> t2
  k_agg<2><<<192, 512, 0, stream>>>(t1, packed, nullptr, nullptr, dis, nullptr,
                                    nullptr, nullptr, nullptr, nullptr,
                                    nullptr, nullptr, Wg2,
                                    t2, nullptr, nullptr, nullptr);
  // 7: GCN agg full-K on t2 + relu*dis -> h2 + ie-lo
  k_agg<0><<<192, 512, 0, stream>>>(t2, packed, nullptr, nullptr, dis, nullptr,
                                    nullptr, nullptr, nullptr, nullptr,
                                    nullptr, nullptr, nullptr,
                                    h2, ie, nullptr, nullptr);
}